// Round 11
// baseline (619.683 us; speedup 1.0000x reference)
//
#include <hip/hip_runtime.h>
#include <math.h>

#define N_NODES 100000
#define N_EDGES 1600000
#define D 128

#define NB 8                 // dst-range buckets == XCD count
#define NODES_PER_B 12500    // N_NODES / NB
#define BUCKET_CAP 262144    // per-bucket capacity (expected 200K)
#define EPB 2048             // edges per pass-1 block
#define P1_BLOCKS ((N_EDGES + EPB - 1) / EPB)   // 782
#define PAD 64               // padded CSR slots per node (P(deg>64) ~ 1e-19)

#define AGG_CHUNKS 1563      // ceil(NODES_PER_B / 8)

#define GEMM_BLOCKS 512      // 2 blocks/CU at 80 KB LDS
#define GEMM_WAVES  (GEMM_BLOCKS * 4)
#define N_TILES     (N_NODES / 8)   // 12500 8-row tiles

// packed bucket entry: bits [16:0] = src, bits [30:17] = dst - bucket*12500
#define PACK(s, dl)  (((unsigned)(dl) << 17) | (unsigned)(s))
#define UNPACK_SRC(v)   ((int)((v) & 0x1FFFFu))
#define UNPACK_DLOC(v)  ((int)((v) >> 17))

// ---------------- pass 1: bucket edges by dst range ----------------

__global__ __launch_bounds__(256) void bucket_edges(
    const int* __restrict__ src, const int* __restrict__ dst,
    int* __restrict__ bucketBase, unsigned* __restrict__ bstore)
{
    __shared__ int cnt[NB];
    __shared__ int base_g[NB];
    __shared__ int sbase[NB + 1];
    __shared__ unsigned stage[EPB];      // 8 KB

    const int tid = threadIdx.x;
    const long long eb = (long long)blockIdx.x * EPB;

    if (tid < NB) cnt[tid] = 0;
    __syncthreads();

    int myb[8], myr[8];
    unsigned mypk[8];
    bool val[8];
#pragma unroll
    for (int i = 0; i < 8; ++i) {
        const long long e = eb + tid + i * 256;
        val[i] = (e < N_EDGES);
        if (val[i]) {
            const int s = src[e];
            const int d = dst[e];
            myb[i] = (int)((unsigned)d / NODES_PER_B);
            mypk[i] = PACK(s, d - myb[i] * NODES_PER_B);
            myr[i] = atomicAdd(&cnt[myb[i]], 1);   // LDS rank
        }
    }
    __syncthreads();

    if (tid == 0) {
        int acc = 0;
#pragma unroll
        for (int b = 0; b < NB; ++b) { sbase[b] = acc; acc += cnt[b]; }
        sbase[NB] = acc;
    }
    __syncthreads();

    if (tid < NB) base_g[tid] = atomicAdd(&bucketBase[tid], cnt[tid]);

#pragma unroll
    for (int i = 0; i < 8; ++i)
        if (val[i]) stage[sbase[myb[i]] + myr[i]] = mypk[i];
    __syncthreads();

    const int total = sbase[NB];
    for (int s = tid; s < total; s += 256) {
        int b = 0;
#pragma unroll
        for (int k = 1; k < NB; ++k) b += (s >= sbase[k]);
        const int gpos = base_g[b] + (s - sbase[b]);
        bstore[(long long)b * BUCKET_CAP + gpos] = stage[s];
    }
}

// ---------------- pass 2: LDS-counter scatter into PADDED CSR ----------------
// ONE block per bucket (8 blocks x 1024 threads). The bucket's whole 12500-entry
// count array lives in LDS -> NO global atomics, no cnt-zeroing pass. csr writes
// are XCD-local (block b -> XCD b, same region agg's affinity reads). Final
// counts written out coalesced at the end.

__global__ __launch_bounds__(1024) void scatter_lds(
    const unsigned* __restrict__ bstore, const int* __restrict__ bucketCount,
    int* __restrict__ cnt, int* __restrict__ csr)
{
    __shared__ int lc[NODES_PER_B];      // 50 KB
    const int b = blockIdx.x;
    const int tid = threadIdx.x;

    for (int i = tid; i < NODES_PER_B; i += 1024) lc[i] = 0;
    __syncthreads();

    const int n = bucketCount[b];
    const unsigned* bs = bstore + (long long)b * BUCKET_CAP;
    const long long cbase = ((long long)b * NODES_PER_B) << 6;   // csr slot base

    // vectorized: 4 packed edges per thread per iteration
    for (int i = tid * 4; i + 4 <= n; i += 1024 * 4) {
        const uint4 v4 = *reinterpret_cast<const uint4*>(&bs[i]);
#pragma unroll
        for (int k = 0; k < 4; ++k) {
            const unsigned v = (k == 0) ? v4.x : (k == 1) ? v4.y : (k == 2) ? v4.z : v4.w;
            const int dl = UNPACK_DLOC(v);
            const int pos = atomicAdd(&lc[dl], 1);
            if (pos < PAD) csr[cbase + ((long long)dl << 6) + pos] = UNPACK_SRC(v);
        }
    }
    // tail (< 4 elements)
    {
        const int t0 = (n >> 2) << 2;
        const int t = t0 + tid;
        if (t < n) {
            const unsigned v = bs[t];
            const int dl = UNPACK_DLOC(v);
            const int pos = atomicAdd(&lc[dl], 1);
            if (pos < PAD) csr[cbase + ((long long)dl << 6) + pos] = UNPACK_SRC(v);
        }
    }
    __syncthreads();

    // write final degrees (coalesced)
    for (int i = tid; i < NODES_PER_B; i += 1024)
        cnt[b * NODES_PER_B + i] = lc[i];
}

// ---------------- aggregation: combined[i] = x[i] + max_{j in N(i)} x[j] ----------------
// XCD-affinity: blockIdx%8 == bucket of the rows it processes. 32 lanes per
// node; 8-deep gather pipeline.

#define FM(M, V) { M.x = fmaxf(M.x, V.x); M.y = fmaxf(M.y, V.y); \
                   M.z = fmaxf(M.z, V.z); M.w = fmaxf(M.w, V.w); }

__global__ __launch_bounds__(256) void agg_combine_kernel(
    const float* __restrict__ x, const int* __restrict__ cnt,
    const int* __restrict__ csr, float* __restrict__ combined)
{
    const int b = blockIdx.x & (NB - 1);
    const int chunk = blockIdx.x >> 3;
    const int ln = threadIdx.x >> 5;            // 0..7 node within block
    const int rl = chunk * 8 + ln;              // node within bucket
    if (rl >= NODES_PER_B) return;
    const int row = b * NODES_PER_B + rl;
    const int col = (threadIdx.x & 31) * 4;

    const int len = min(cnt[row], PAD);
    const int beg = row << 6;                   // PAD = 64
    const int end = beg + len;

    // hoist self-row load: in flight during the whole gather loop
    const float4 xv = *reinterpret_cast<const float4*>(&x[(long long)row * D + col]);

    float4 m0 = make_float4(-INFINITY, -INFINITY, -INFINITY, -INFINITY);
    float4 m1 = m0, m2 = m0, m3 = m0;

    int j = beg;
    // ---- 8-edge chunks: 2 index loads up front, 8 gathers in flight ----
    for (; j + 8 <= end; j += 8) {
        const int4 sa = *reinterpret_cast<const int4*>(&csr[j]);
        const int4 sb = *reinterpret_cast<const int4*>(&csr[j + 4]);
        const float4 v0 = *reinterpret_cast<const float4*>(&x[(long long)sa.x * D + col]);
        const float4 v1 = *reinterpret_cast<const float4*>(&x[(long long)sa.y * D + col]);
        const float4 v2 = *reinterpret_cast<const float4*>(&x[(long long)sa.z * D + col]);
        const float4 v3 = *reinterpret_cast<const float4*>(&x[(long long)sa.w * D + col]);
        const float4 v4 = *reinterpret_cast<const float4*>(&x[(long long)sb.x * D + col]);
        const float4 v5 = *reinterpret_cast<const float4*>(&x[(long long)sb.y * D + col]);
        const float4 v6 = *reinterpret_cast<const float4*>(&x[(long long)sb.z * D + col]);
        const float4 v7 = *reinterpret_cast<const float4*>(&x[(long long)sb.w * D + col]);
        FM(m0, v0); FM(m1, v1); FM(m2, v2); FM(m3, v3);
        FM(m0, v4); FM(m1, v5); FM(m2, v6); FM(m3, v7);
    }
    // ---- 4-edge chunk ----
    if (j + 4 <= end) {
        const int4 sa = *reinterpret_cast<const int4*>(&csr[j]);
        const float4 v0 = *reinterpret_cast<const float4*>(&x[(long long)sa.x * D + col]);
        const float4 v1 = *reinterpret_cast<const float4*>(&x[(long long)sa.y * D + col]);
        const float4 v2 = *reinterpret_cast<const float4*>(&x[(long long)sa.z * D + col]);
        const float4 v3 = *reinterpret_cast<const float4*>(&x[(long long)sa.w * D + col]);
        FM(m0, v0); FM(m1, v1); FM(m2, v2); FM(m3, v3);
        j += 4;
    }
    // ---- scalar tail (<=3) ----
    for (; j < end; ++j) {
        const int s = csr[j];
        const float4 v = *reinterpret_cast<const float4*>(&x[(long long)s * D + col]);
        FM(m0, v);
    }

    m0.x = fmaxf(fmaxf(m0.x, m1.x), fmaxf(m2.x, m3.x));
    m0.y = fmaxf(fmaxf(m0.y, m1.y), fmaxf(m2.y, m3.y));
    m0.z = fmaxf(fmaxf(m0.z, m1.z), fmaxf(m2.z, m3.z));
    m0.w = fmaxf(fmaxf(m0.w, m1.w), fmaxf(m2.w, m3.w));

    float4 c;
    if (len > 0) {
        c.x = xv.x + m0.x; c.y = xv.y + m0.y; c.z = xv.z + m0.z; c.w = xv.w + m0.w;
    } else {
        c = xv;   // empty neighborhood -> agg = 0
    }
    *reinterpret_cast<float4*>(&combined[(long long)row * D + col]) = c;
}

#undef FM

// ---------------- persistent GEMM: out = [relu](combined @ W + b) ----------------
// 512 blocks (2/CU), W staged ONCE per block. After the single W barrier, each
// WAVE independently grid-strides over 8-row tiles (intra-wave LDS dep only).

template<bool RELU>
__global__ __launch_bounds__(256, 2) void gin_gemm_persist(
    const float* __restrict__ xc, const float* __restrict__ W,
    const float* __restrict__ b, float* __restrict__ out)
{
    __shared__ float Wlds[D * D];        // 64 KB
    __shared__ float rowbuf[4][8][D];    // 16 KB, per-wave slice

    const int tid = threadIdx.x;

    for (int i = tid * 4; i < D * D; i += 256 * 4) {
        *reinterpret_cast<float4*>(&Wlds[i]) = *reinterpret_cast<const float4*>(&W[i]);
    }
    __syncthreads();                     // the only block-wide barrier

    const int wave = tid >> 6;
    const int lane = tid & 63;
    const int half = lane >> 5;
    const int col  = (lane & 31) * 4;
    const int r0   = half * 4;           // local row base within wave's 8 rows
    const int gw   = blockIdx.x * 4 + wave;   // global wave id

    const float4 bias = *reinterpret_cast<const float4*>(&b[col]);
    float (*rb)[D] = rowbuf[wave];

    for (int t = gw; t < N_TILES; t += GEMM_WAVES) {
        const int rbase = t * 8;

        // stage this wave's 8 rows (256 float4 / 64 lanes = 4 each, coalesced)
#pragma unroll
        for (int i = 0; i < 4; ++i) {
            const int idx = lane + i * 64;        // 0..255
            const int rl  = idx >> 5;
            const int c4  = (idx & 31) * 4;
            *reinterpret_cast<float4*>(&rb[rl][c4]) =
                *reinterpret_cast<const float4*>(&xc[(long long)(rbase + rl) * D + c4]);
        }
        // intra-wave LDS dep: compiler inserts lgkmcnt wait before reads

        float4 acc0 = bias, acc1 = bias, acc2 = bias, acc3 = bias;

#define GEMM_STEP(K, XA, XB, XC, XD)                                        \
    {                                                                       \
        const float4 w4 = *reinterpret_cast<const float4*>(&Wlds[(K) * D + col]); \
        acc0.x = fmaf(XA, w4.x, acc0.x); acc0.y = fmaf(XA, w4.y, acc0.y);   \
        acc0.z = fmaf(XA, w4.z, acc0.z); acc0.w = fmaf(XA, w4.w, acc0.w);   \
        acc1.x = fmaf(XB, w4.x, acc1.x); acc1.y = fmaf(XB, w4.y, acc1.y);   \
        acc1.z = fmaf(XB, w4.z, acc1.z); acc1.w = fmaf(XB, w4.w, acc1.w);   \
        acc2.x = fmaf(XC, w4.x, acc2.x); acc2.y = fmaf(XC, w4.y, acc2.y);   \
        acc2.z = fmaf(XC, w4.z, acc2.z); acc2.w = fmaf(XC, w4.w, acc2.w);   \
        acc3.x = fmaf(XD, w4.x, acc3.x); acc3.y = fmaf(XD, w4.y, acc3.y);   \
        acc3.z = fmaf(XD, w4.z, acc3.z); acc3.w = fmaf(XD, w4.w, acc3.w);   \
    }

#pragma unroll 4
        for (int kg = 0; kg < D; kg += 4) {
            const float4 xa  = *reinterpret_cast<const float4*>(&rb[r0 + 0][kg]);
            const float4 xb  = *reinterpret_cast<const float4*>(&rb[r0 + 1][kg]);
            const float4 xc4 = *reinterpret_cast<const float4*>(&rb[r0 + 2][kg]);
            const float4 xd  = *reinterpret_cast<const float4*>(&rb[r0 + 3][kg]);
            GEMM_STEP(kg + 0, xa.x, xb.x, xc4.x, xd.x);
            GEMM_STEP(kg + 1, xa.y, xb.y, xc4.y, xd.y);
            GEMM_STEP(kg + 2, xa.z, xb.z, xc4.z, xd.z);
            GEMM_STEP(kg + 3, xa.w, xb.w, xc4.w, xd.w);
        }
#undef GEMM_STEP

        if (RELU) {
            acc0.x = fmaxf(acc0.x, 0.f); acc0.y = fmaxf(acc0.y, 0.f); acc0.z = fmaxf(acc0.z, 0.f); acc0.w = fmaxf(acc0.w, 0.f);
            acc1.x = fmaxf(acc1.x, 0.f); acc1.y = fmaxf(acc1.y, 0.f); acc1.z = fmaxf(acc1.z, 0.f); acc1.w = fmaxf(acc1.w, 0.f);
            acc2.x = fmaxf(acc2.x, 0.f); acc2.y = fmaxf(acc2.y, 0.f); acc2.z = fmaxf(acc2.z, 0.f); acc2.w = fmaxf(acc2.w, 0.f);
            acc3.x = fmaxf(acc3.x, 0.f); acc3.y = fmaxf(acc3.y, 0.f); acc3.z = fmaxf(acc3.z, 0.f); acc3.w = fmaxf(acc3.w, 0.f);
        }

        float* o = &out[(long long)(rbase + r0) * D + col];
        *reinterpret_cast<float4*>(&o[0 * D]) = acc0;
        *reinterpret_cast<float4*>(&o[1 * D]) = acc1;
        *reinterpret_cast<float4*>(&o[2 * D]) = acc2;
        *reinterpret_cast<float4*>(&o[3 * D]) = acc3;
    }
}

// ---------------- launch ----------------

extern "C" void kernel_launch(void* const* d_in, const int* in_sizes, int n_in,
                              void* d_out, int out_size, void* d_ws, size_t ws_size,
                              hipStream_t stream) {
    const float* h   = (const float*)d_in[0];
    const int*   src = (const int*)d_in[1];
    const int*   dst = (const int*)d_in[2];
    const float* W1  = (const float*)d_in[3];
    const float* b1  = (const float*)d_in[4];
    const float* W2  = (const float*)d_in[5];
    const float* b2  = (const float*)d_in[6];
    float* out = (float*)d_out;

    // workspace layout (16B aligned chunks)
    int* cnt         = (int*)d_ws;                            // [100352]
    int* bucketBase  = cnt + 100352;                          // [512 reserved; 8 used]
    int* csr         = bucketBase + 512;                      // [N * PAD] = 25.6 MB
    unsigned* bstore = (unsigned*)(csr + (size_t)N_NODES * PAD); // [8 * 262144] = 8 MB
    float* combined  = (float*)(bstore + (size_t)NB * BUCKET_CAP); // [N*D]
    float* x1        = combined + (size_t)N_NODES * D;             // [N*D]

    // ---- CSR build: tiny memset + bucket + LDS-counter scatter ----
    hipMemsetAsync(bucketBase, 0, NB * sizeof(int), stream);
    bucket_edges<<<P1_BLOCKS, 256, 0, stream>>>(src, dst, bucketBase, bstore);
    scatter_lds<<<NB, 1024, 0, stream>>>(bstore, bucketBase, cnt, csr);

    // ---- layer 1 ----
    agg_combine_kernel<<<NB * AGG_CHUNKS, 256, 0, stream>>>(h, cnt, csr, combined);
    gin_gemm_persist<true><<<GEMM_BLOCKS, 256, 0, stream>>>(combined, W1, b1, x1);

    // ---- layer 2 ----
    agg_combine_kernel<<<NB * AGG_CHUNKS, 256, 0, stream>>>(x1, cnt, csr, combined);
    gin_gemm_persist<false><<<GEMM_BLOCKS, 256, 0, stream>>>(combined, W2, b2, out);
}

// Round 12
// 503.621 us; speedup vs baseline: 1.2305x; 1.2305x over previous
//
#include <hip/hip_runtime.h>
#include <math.h>

#define N_NODES 100000
#define N_EDGES 1600000
#define D 128

#define NB 8                 // dst-range buckets == XCD count
#define NODES_PER_B 12500    // N_NODES / NB
#define BUCKET_CAP 262144    // per-bucket capacity (expected 200K)
#define EPB 2048             // edges per pass-1 block
#define P1_BLOCKS ((N_EDGES + EPB - 1) / EPB)   // 782
#define PAD 64               // padded CSR slots per node (P(deg>64) ~ 1e-19)

#define SC_CHUNKS 16         // node-range chunks per bucket for scatter
#define CHUNK_N   782        // ceil(NODES_PER_B / SC_CHUNKS)

#define AGG_CHUNKS 1563      // ceil(NODES_PER_B / 8)

#define GEMM_BLOCKS 512      // 2 blocks/CU at 80 KB LDS
#define GEMM_WAVES  (GEMM_BLOCKS * 4)
#define N_TILES     (N_NODES / 8)   // 12500 8-row tiles

// packed bucket entry: bits [16:0] = src, bits [30:17] = dst - bucket*12500
#define PACK(s, dl)  (((unsigned)(dl) << 17) | (unsigned)(s))
#define UNPACK_SRC(v)   ((int)((v) & 0x1FFFFu))
#define UNPACK_DLOC(v)  ((int)((v) >> 17))

// ---------------- pass 1: bucket edges by dst range ----------------

__global__ __launch_bounds__(256) void bucket_edges(
    const int* __restrict__ src, const int* __restrict__ dst,
    int* __restrict__ bucketBase, unsigned* __restrict__ bstore)
{
    __shared__ int cnt[NB];
    __shared__ int base_g[NB];
    __shared__ int sbase[NB + 1];
    __shared__ unsigned stage[EPB];      // 8 KB

    const int tid = threadIdx.x;
    const long long eb = (long long)blockIdx.x * EPB;

    if (tid < NB) cnt[tid] = 0;
    __syncthreads();

    int myb[8], myr[8];
    unsigned mypk[8];
    bool val[8];
#pragma unroll
    for (int i = 0; i < 8; ++i) {
        const long long e = eb + tid + i * 256;
        val[i] = (e < N_EDGES);
        if (val[i]) {
            const int s = src[e];
            const int d = dst[e];
            myb[i] = (int)((unsigned)d / NODES_PER_B);
            mypk[i] = PACK(s, d - myb[i] * NODES_PER_B);
            myr[i] = atomicAdd(&cnt[myb[i]], 1);   // LDS rank
        }
    }
    __syncthreads();

    if (tid == 0) {
        int acc = 0;
#pragma unroll
        for (int b = 0; b < NB; ++b) { sbase[b] = acc; acc += cnt[b]; }
        sbase[NB] = acc;
    }
    __syncthreads();

    if (tid < NB) base_g[tid] = atomicAdd(&bucketBase[tid], cnt[tid]);

#pragma unroll
    for (int i = 0; i < 8; ++i)
        if (val[i]) stage[sbase[myb[i]] + myr[i]] = mypk[i];
    __syncthreads();

    const int total = sbase[NB];
    for (int s = tid; s < total; s += 256) {
        int b = 0;
#pragma unroll
        for (int k = 1; k < NB; ++k) b += (s >= sbase[k]);
        const int gpos = base_g[b] + (s - sbase[b]);
        bstore[(long long)b * BUCKET_CAP + gpos] = stage[s];
    }
}

// ---------------- pass 2: filtered-scan LDS-counter scatter ----------------
// Grid = NB buckets x SC_CHUNKS node-range chunks = 128 blocks x 1024 threads.
// Block (b,c) scans bucket b's full packed list (XCD-local L2 after first
// fetch, since blockIdx%8==b) and keeps only edges with dst in its 782-node
// chunk -> LDS counters (3.1 KB), no global atomics, no cnt-zeroing pass.

__global__ __launch_bounds__(1024) void scatter_filter(
    const unsigned* __restrict__ bstore, const int* __restrict__ bucketCount,
    int* __restrict__ cnt, int* __restrict__ csr)
{
    __shared__ int lc[CHUNK_N];
    const int b  = blockIdx.x & (NB - 1);
    const int c  = blockIdx.x >> 3;            // 0..SC_CHUNKS-1
    const int lo = c * CHUNK_N;
    const int hi = min(lo + CHUNK_N, NODES_PER_B);
    const int nn = hi - lo;
    const int tid = threadIdx.x;

    for (int i = tid; i < nn; i += 1024) lc[i] = 0;
    __syncthreads();

    const int n = bucketCount[b];
    const unsigned* bs = bstore + (long long)b * BUCKET_CAP;
    const long long cbase = ((long long)b * NODES_PER_B) << 6;   // csr slot base

    // vectorized scan: 4 packed edges per thread per iteration
    for (int i = tid * 4; i + 4 <= n; i += 1024 * 4) {
        const uint4 v4 = *reinterpret_cast<const uint4*>(&bs[i]);
#pragma unroll
        for (int k = 0; k < 4; ++k) {
            const unsigned v = (k == 0) ? v4.x : (k == 1) ? v4.y : (k == 2) ? v4.z : v4.w;
            const int dl = UNPACK_DLOC(v);
            if (dl >= lo && dl < hi) {
                const int pos = atomicAdd(&lc[dl - lo], 1);
                if (pos < PAD) csr[cbase + ((long long)dl << 6) + pos] = UNPACK_SRC(v);
            }
        }
    }
    // scalar tail (< 4 elements)
    {
        const int t = (n & ~3) + tid;
        if (t < n) {
            const unsigned v = bs[t];
            const int dl = UNPACK_DLOC(v);
            if (dl >= lo && dl < hi) {
                const int pos = atomicAdd(&lc[dl - lo], 1);
                if (pos < PAD) csr[cbase + ((long long)dl << 6) + pos] = UNPACK_SRC(v);
            }
        }
    }
    __syncthreads();

    // write final degrees for this chunk (coalesced; covers zeros too)
    for (int i = tid; i < nn; i += 1024)
        cnt[b * NODES_PER_B + lo + i] = lc[i];
}

// ---------------- aggregation: combined[i] = x[i] + max_{j in N(i)} x[j] ----------------
// XCD-affinity: blockIdx%8 == bucket of the rows it processes. 32 lanes per
// node; 8-deep gather pipeline.

#define FM(M, V) { M.x = fmaxf(M.x, V.x); M.y = fmaxf(M.y, V.y); \
                   M.z = fmaxf(M.z, V.z); M.w = fmaxf(M.w, V.w); }

__global__ __launch_bounds__(256) void agg_combine_kernel(
    const float* __restrict__ x, const int* __restrict__ cnt,
    const int* __restrict__ csr, float* __restrict__ combined)
{
    const int b = blockIdx.x & (NB - 1);
    const int chunk = blockIdx.x >> 3;
    const int ln = threadIdx.x >> 5;            // 0..7 node within block
    const int rl = chunk * 8 + ln;              // node within bucket
    if (rl >= NODES_PER_B) return;
    const int row = b * NODES_PER_B + rl;
    const int col = (threadIdx.x & 31) * 4;

    const int len = min(cnt[row], PAD);
    const int beg = row << 6;                   // PAD = 64
    const int end = beg + len;

    // hoist self-row load: in flight during the whole gather loop
    const float4 xv = *reinterpret_cast<const float4*>(&x[(long long)row * D + col]);

    float4 m0 = make_float4(-INFINITY, -INFINITY, -INFINITY, -INFINITY);
    float4 m1 = m0, m2 = m0, m3 = m0;

    int j = beg;
    // ---- 8-edge chunks: 2 index loads up front, 8 gathers in flight ----
    for (; j + 8 <= end; j += 8) {
        const int4 sa = *reinterpret_cast<const int4*>(&csr[j]);
        const int4 sb = *reinterpret_cast<const int4*>(&csr[j + 4]);
        const float4 v0 = *reinterpret_cast<const float4*>(&x[(long long)sa.x * D + col]);
        const float4 v1 = *reinterpret_cast<const float4*>(&x[(long long)sa.y * D + col]);
        const float4 v2 = *reinterpret_cast<const float4*>(&x[(long long)sa.z * D + col]);
        const float4 v3 = *reinterpret_cast<const float4*>(&x[(long long)sa.w * D + col]);
        const float4 v4 = *reinterpret_cast<const float4*>(&x[(long long)sb.x * D + col]);
        const float4 v5 = *reinterpret_cast<const float4*>(&x[(long long)sb.y * D + col]);
        const float4 v6 = *reinterpret_cast<const float4*>(&x[(long long)sb.z * D + col]);
        const float4 v7 = *reinterpret_cast<const float4*>(&x[(long long)sb.w * D + col]);
        FM(m0, v0); FM(m1, v1); FM(m2, v2); FM(m3, v3);
        FM(m0, v4); FM(m1, v5); FM(m2, v6); FM(m3, v7);
    }
    // ---- 4-edge chunk ----
    if (j + 4 <= end) {
        const int4 sa = *reinterpret_cast<const int4*>(&csr[j]);
        const float4 v0 = *reinterpret_cast<const float4*>(&x[(long long)sa.x * D + col]);
        const float4 v1 = *reinterpret_cast<const float4*>(&x[(long long)sa.y * D + col]);
        const float4 v2 = *reinterpret_cast<const float4*>(&x[(long long)sa.z * D + col]);
        const float4 v3 = *reinterpret_cast<const float4*>(&x[(long long)sa.w * D + col]);
        FM(m0, v0); FM(m1, v1); FM(m2, v2); FM(m3, v3);
        j += 4;
    }
    // ---- scalar tail (<=3) ----
    for (; j < end; ++j) {
        const int s = csr[j];
        const float4 v = *reinterpret_cast<const float4*>(&x[(long long)s * D + col]);
        FM(m0, v);
    }

    m0.x = fmaxf(fmaxf(m0.x, m1.x), fmaxf(m2.x, m3.x));
    m0.y = fmaxf(fmaxf(m0.y, m1.y), fmaxf(m2.y, m3.y));
    m0.z = fmaxf(fmaxf(m0.z, m1.z), fmaxf(m2.z, m3.z));
    m0.w = fmaxf(fmaxf(m0.w, m1.w), fmaxf(m2.w, m3.w));

    float4 c;
    if (len > 0) {
        c.x = xv.x + m0.x; c.y = xv.y + m0.y; c.z = xv.z + m0.z; c.w = xv.w + m0.w;
    } else {
        c = xv;   // empty neighborhood -> agg = 0
    }
    *reinterpret_cast<float4*>(&combined[(long long)row * D + col]) = c;
}

#undef FM

// ---------------- persistent GEMM: out = [relu](combined @ W + b) ----------------
// 512 blocks (2/CU), W staged ONCE per block. After the single W barrier, each
// WAVE independently grid-strides over 8-row tiles (intra-wave LDS dep only).

template<bool RELU>
__global__ __launch_bounds__(256, 2) void gin_gemm_persist(
    const float* __restrict__ xc, const float* __restrict__ W,
    const float* __restrict__ b, float* __restrict__ out)
{
    __shared__ float Wlds[D * D];        // 64 KB
    __shared__ float rowbuf[4][8][D];    // 16 KB, per-wave slice

    const int tid = threadIdx.x;

    for (int i = tid * 4; i < D * D; i += 256 * 4) {
        *reinterpret_cast<float4*>(&Wlds[i]) = *reinterpret_cast<const float4*>(&W[i]);
    }
    __syncthreads();                     // the only block-wide barrier

    const int wave = tid >> 6;
    const int lane = tid & 63;
    const int half = lane >> 5;
    const int col  = (lane & 31) * 4;
    const int r0   = half * 4;           // local row base within wave's 8 rows
    const int gw   = blockIdx.x * 4 + wave;   // global wave id

    const float4 bias = *reinterpret_cast<const float4*>(&b[col]);
    float (*rb)[D] = rowbuf[wave];

    for (int t = gw; t < N_TILES; t += GEMM_WAVES) {
        const int rbase = t * 8;

        // stage this wave's 8 rows (256 float4 / 64 lanes = 4 each, coalesced)
#pragma unroll
        for (int i = 0; i < 4; ++i) {
            const int idx = lane + i * 64;        // 0..255
            const int rl  = idx >> 5;
            const int c4  = (idx & 31) * 4;
            *reinterpret_cast<float4*>(&rb[rl][c4]) =
                *reinterpret_cast<const float4*>(&xc[(long long)(rbase + rl) * D + c4]);
        }
        // intra-wave LDS dep: compiler inserts lgkmcnt wait before reads

        float4 acc0 = bias, acc1 = bias, acc2 = bias, acc3 = bias;

#define GEMM_STEP(K, XA, XB, XC, XD)                                        \
    {                                                                       \
        const float4 w4 = *reinterpret_cast<const float4*>(&Wlds[(K) * D + col]); \
        acc0.x = fmaf(XA, w4.x, acc0.x); acc0.y = fmaf(XA, w4.y, acc0.y);   \
        acc0.z = fmaf(XA, w4.z, acc0.z); acc0.w = fmaf(XA, w4.w, acc0.w);   \
        acc1.x = fmaf(XB, w4.x, acc1.x); acc1.y = fmaf(XB, w4.y, acc1.y);   \
        acc1.z = fmaf(XB, w4.z, acc1.z); acc1.w = fmaf(XB, w4.w, acc1.w);   \
        acc2.x = fmaf(XC, w4.x, acc2.x); acc2.y = fmaf(XC, w4.y, acc2.y);   \
        acc2.z = fmaf(XC, w4.z, acc2.z); acc2.w = fmaf(XC, w4.w, acc2.w);   \
        acc3.x = fmaf(XD, w4.x, acc3.x); acc3.y = fmaf(XD, w4.y, acc3.y);   \
        acc3.z = fmaf(XD, w4.z, acc3.z); acc3.w = fmaf(XD, w4.w, acc3.w);   \
    }

#pragma unroll 4
        for (int kg = 0; kg < D; kg += 4) {
            const float4 xa  = *reinterpret_cast<const float4*>(&rb[r0 + 0][kg]);
            const float4 xb  = *reinterpret_cast<const float4*>(&rb[r0 + 1][kg]);
            const float4 xc4 = *reinterpret_cast<const float4*>(&rb[r0 + 2][kg]);
            const float4 xd  = *reinterpret_cast<const float4*>(&rb[r0 + 3][kg]);
            GEMM_STEP(kg + 0, xa.x, xb.x, xc4.x, xd.x);
            GEMM_STEP(kg + 1, xa.y, xb.y, xc4.y, xd.y);
            GEMM_STEP(kg + 2, xa.z, xb.z, xc4.z, xd.z);
            GEMM_STEP(kg + 3, xa.w, xb.w, xc4.w, xd.w);
        }
#undef GEMM_STEP

        if (RELU) {
            acc0.x = fmaxf(acc0.x, 0.f); acc0.y = fmaxf(acc0.y, 0.f); acc0.z = fmaxf(acc0.z, 0.f); acc0.w = fmaxf(acc0.w, 0.f);
            acc1.x = fmaxf(acc1.x, 0.f); acc1.y = fmaxf(acc1.y, 0.f); acc1.z = fmaxf(acc1.z, 0.f); acc1.w = fmaxf(acc1.w, 0.f);
            acc2.x = fmaxf(acc2.x, 0.f); acc2.y = fmaxf(acc2.y, 0.f); acc2.z = fmaxf(acc2.z, 0.f); acc2.w = fmaxf(acc2.w, 0.f);
            acc3.x = fmaxf(acc3.x, 0.f); acc3.y = fmaxf(acc3.y, 0.f); acc3.z = fmaxf(acc3.z, 0.f); acc3.w = fmaxf(acc3.w, 0.f);
        }

        float* o = &out[(long long)(rbase + r0) * D + col];
        *reinterpret_cast<float4*>(&o[0 * D]) = acc0;
        *reinterpret_cast<float4*>(&o[1 * D]) = acc1;
        *reinterpret_cast<float4*>(&o[2 * D]) = acc2;
        *reinterpret_cast<float4*>(&o[3 * D]) = acc3;
    }
}

// ---------------- launch ----------------

extern "C" void kernel_launch(void* const* d_in, const int* in_sizes, int n_in,
                              void* d_out, int out_size, void* d_ws, size_t ws_size,
                              hipStream_t stream) {
    const float* h   = (const float*)d_in[0];
    const int*   src = (const int*)d_in[1];
    const int*   dst = (const int*)d_in[2];
    const float* W1  = (const float*)d_in[3];
    const float* b1  = (const float*)d_in[4];
    const float* W2  = (const float*)d_in[5];
    const float* b2  = (const float*)d_in[6];
    float* out = (float*)d_out;

    // workspace layout (16B aligned chunks)
    int* cnt         = (int*)d_ws;                            // [100352]
    int* bucketBase  = cnt + 100352;                          // [512 reserved; 8 used]
    int* csr         = bucketBase + 512;                      // [N * PAD] = 25.6 MB
    unsigned* bstore = (unsigned*)(csr + (size_t)N_NODES * PAD); // [8 * 262144] = 8 MB
    float* combined  = (float*)(bstore + (size_t)NB * BUCKET_CAP); // [N*D]
    float* x1        = combined + (size_t)N_NODES * D;             // [N*D]

    // ---- CSR build: tiny memset + bucket + filtered LDS-counter scatter ----
    hipMemsetAsync(bucketBase, 0, NB * sizeof(int), stream);
    bucket_edges<<<P1_BLOCKS, 256, 0, stream>>>(src, dst, bucketBase, bstore);
    scatter_filter<<<NB * SC_CHUNKS, 1024, 0, stream>>>(bstore, bucketBase, cnt, csr);

    // ---- layer 1 ----
    agg_combine_kernel<<<NB * AGG_CHUNKS, 256, 0, stream>>>(h, cnt, csr, combined);
    gin_gemm_persist<true><<<GEMM_BLOCKS, 256, 0, stream>>>(combined, W1, b1, x1);

    // ---- layer 2 ----
    agg_combine_kernel<<<NB * AGG_CHUNKS, 256, 0, stream>>>(x1, cnt, csr, combined);
    gin_gemm_persist<false><<<GEMM_BLOCKS, 256, 0, stream>>>(combined, W2, b2, out);
}

// Round 13
// 399.596 us; speedup vs baseline: 1.5508x; 1.2603x over previous
//
#include <hip/hip_runtime.h>
#include <math.h>

#define N_NODES 100000
#define N_EDGES 1600000
#define D 128

#define NB 8                 // dst-range buckets == XCD count
#define NODES_PER_B 12500    // N_NODES / NB
#define BUCKET_CAP 262144    // per-bucket capacity (expected 200K)
#define EPB 2048             // edges per pass-1 block
#define P1_BLOCKS ((N_EDGES + EPB - 1) / EPB)   // 782
#define PAD 64               // padded CSR slots per node (P(deg>64) ~ 1e-19)

#define SC_CHUNKS 16         // node-range chunks per bucket for scatter
#define CHUNK_N   782        // ceil(NODES_PER_B / SC_CHUNKS)

#define AGG_CHUNKS 1563      // ceil(NODES_PER_B / 8)

#define GEMM_BLOCKS 512      // 2 blocks/CU at 80 KB LDS
#define GEMM_WAVES  (GEMM_BLOCKS * 4)
#define N_TILES     (N_NODES / 8)   // 12500 8-row tiles

// packed bucket entry: bits [16:0] = src, bits [30:17] = dst - bucket*12500
#define PACK(s, dl)  (((unsigned)(dl) << 17) | (unsigned)(s))
#define UNPACK_SRC(v)   ((int)((v) & 0x1FFFFu))
#define UNPACK_DLOC(v)  ((int)((v) >> 17))

// RNE float -> bf16 (no NaN in inputs)
__device__ __forceinline__ unsigned short f2bf(float f) {
    const unsigned u = __float_as_uint(f);
    return (unsigned short)((u + 0x7FFFu + ((u >> 16) & 1u)) >> 16);
}
__device__ __forceinline__ unsigned pack2bf(float a, float b) {
    return (unsigned)f2bf(a) | ((unsigned)f2bf(b) << 16);
}
__device__ __forceinline__ float bf2f(unsigned short u) {
    return __uint_as_float(((unsigned)u) << 16);
}

// ---------------- pass 1: bucket edges by dst range (+ h -> bf16 mirror) ----------------

__global__ __launch_bounds__(256) void bucket_edges(
    const int* __restrict__ src, const int* __restrict__ dst,
    int* __restrict__ bucketBase, unsigned* __restrict__ bstore,
    const float* __restrict__ h, uint4* __restrict__ xb4)
{
    __shared__ int cnt[NB];
    __shared__ int base_g[NB];
    __shared__ int sbase[NB + 1];
    __shared__ unsigned stage[EPB];      // 8 KB

    const int tid = threadIdx.x;
    const long long eb = (long long)blockIdx.x * EPB;

    // fold h -> bf16 conversion: grid-stride over 1.6M uint4 groups (8 floats each)
    for (int g = blockIdx.x * 256 + tid; g < (N_NODES * D / 8); g += P1_BLOCKS * 256) {
        const float4 a = *reinterpret_cast<const float4*>(&h[(long long)g * 8]);
        const float4 b = *reinterpret_cast<const float4*>(&h[(long long)g * 8 + 4]);
        uint4 o;
        o.x = pack2bf(a.x, a.y); o.y = pack2bf(a.z, a.w);
        o.z = pack2bf(b.x, b.y); o.w = pack2bf(b.z, b.w);
        xb4[g] = o;
    }

    if (tid < NB) cnt[tid] = 0;
    __syncthreads();

    int myb[8], myr[8];
    unsigned mypk[8];
    bool val[8];
#pragma unroll
    for (int i = 0; i < 8; ++i) {
        const long long e = eb + tid + i * 256;
        val[i] = (e < N_EDGES);
        if (val[i]) {
            const int s = src[e];
            const int d = dst[e];
            myb[i] = (int)((unsigned)d / NODES_PER_B);
            mypk[i] = PACK(s, d - myb[i] * NODES_PER_B);
            myr[i] = atomicAdd(&cnt[myb[i]], 1);   // LDS rank
        }
    }
    __syncthreads();

    if (tid == 0) {
        int acc = 0;
#pragma unroll
        for (int b = 0; b < NB; ++b) { sbase[b] = acc; acc += cnt[b]; }
        sbase[NB] = acc;
    }
    __syncthreads();

    if (tid < NB) base_g[tid] = atomicAdd(&bucketBase[tid], cnt[tid]);

#pragma unroll
    for (int i = 0; i < 8; ++i)
        if (val[i]) stage[sbase[myb[i]] + myr[i]] = mypk[i];
    __syncthreads();

    const int total = sbase[NB];
    for (int s = tid; s < total; s += 256) {
        int b = 0;
#pragma unroll
        for (int k = 1; k < NB; ++k) b += (s >= sbase[k]);
        const int gpos = base_g[b] + (s - sbase[b]);
        bstore[(long long)b * BUCKET_CAP + gpos] = stage[s];
    }
}

// ---------------- pass 2: filtered-scan LDS-counter scatter ----------------

__global__ __launch_bounds__(1024) void scatter_filter(
    const unsigned* __restrict__ bstore, const int* __restrict__ bucketCount,
    int* __restrict__ cnt, int* __restrict__ csr)
{
    __shared__ int lc[CHUNK_N];
    const int b  = blockIdx.x & (NB - 1);
    const int c  = blockIdx.x >> 3;            // 0..SC_CHUNKS-1
    const int lo = c * CHUNK_N;
    const int hi = min(lo + CHUNK_N, NODES_PER_B);
    const int nn = hi - lo;
    const int tid = threadIdx.x;

    for (int i = tid; i < nn; i += 1024) lc[i] = 0;
    __syncthreads();

    const int n = bucketCount[b];
    const unsigned* bs = bstore + (long long)b * BUCKET_CAP;
    const long long cbase = ((long long)b * NODES_PER_B) << 6;   // csr slot base

    for (int i = tid * 4; i + 4 <= n; i += 1024 * 4) {
        const uint4 v4 = *reinterpret_cast<const uint4*>(&bs[i]);
#pragma unroll
        for (int k = 0; k < 4; ++k) {
            const unsigned v = (k == 0) ? v4.x : (k == 1) ? v4.y : (k == 2) ? v4.z : v4.w;
            const int dl = UNPACK_DLOC(v);
            if (dl >= lo && dl < hi) {
                const int pos = atomicAdd(&lc[dl - lo], 1);
                if (pos < PAD) csr[cbase + ((long long)dl << 6) + pos] = UNPACK_SRC(v);
            }
        }
    }
    {
        const int t = (n & ~3) + tid;
        if (t < n) {
            const unsigned v = bs[t];
            const int dl = UNPACK_DLOC(v);
            if (dl >= lo && dl < hi) {
                const int pos = atomicAdd(&lc[dl - lo], 1);
                if (pos < PAD) csr[cbase + ((long long)dl << 6) + pos] = UNPACK_SRC(v);
            }
        }
    }
    __syncthreads();

    for (int i = tid; i < nn; i += 1024)
        cnt[b * NODES_PER_B + lo + i] = lc[i];
}

// ---------------- aggregation: combined[i] = x[i] + max_{j in N(i)} xb[j] ----------------
// bf16 GATHER (halves bytes + L2 lines); fp32 self-row; fp32 max after free
// <<16 conversion. RNE is monotone -> result == bf16(true fp32 max) exactly.

#define BFM(M, U) { M.x = fmaxf(M.x, bf2f(U.x)); M.y = fmaxf(M.y, bf2f(U.y)); \
                    M.z = fmaxf(M.z, bf2f(U.z)); M.w = fmaxf(M.w, bf2f(U.w)); }

__global__ __launch_bounds__(256) void agg_combine_kernel(
    const float* __restrict__ x, const unsigned short* __restrict__ xb,
    const int* __restrict__ cnt, const int* __restrict__ csr,
    float* __restrict__ combined)
{
    const int b = blockIdx.x & (NB - 1);
    const int chunk = blockIdx.x >> 3;
    const int ln = threadIdx.x >> 5;            // 0..7 node within block
    const int rl = chunk * 8 + ln;              // node within bucket
    if (rl >= NODES_PER_B) return;
    const int row = b * NODES_PER_B + rl;
    const int col = (threadIdx.x & 31) * 4;

    const int len = min(cnt[row], PAD);
    const int beg = row << 6;                   // PAD = 64
    const int end = beg + len;

    // hoist self-row load (fp32, exact): in flight during the whole gather loop
    const float4 xv = *reinterpret_cast<const float4*>(&x[(long long)row * D + col]);

    float4 m0 = make_float4(-INFINITY, -INFINITY, -INFINITY, -INFINITY);
    float4 m1 = m0, m2 = m0, m3 = m0;

    int j = beg;
    // ---- 8-edge chunks: 2 index loads up front, 8 bf16 gathers in flight ----
    for (; j + 8 <= end; j += 8) {
        const int4 sa = *reinterpret_cast<const int4*>(&csr[j]);
        const int4 sb = *reinterpret_cast<const int4*>(&csr[j + 4]);
        const ushort4 v0 = *reinterpret_cast<const ushort4*>(&xb[(long long)sa.x * D + col]);
        const ushort4 v1 = *reinterpret_cast<const ushort4*>(&xb[(long long)sa.y * D + col]);
        const ushort4 v2 = *reinterpret_cast<const ushort4*>(&xb[(long long)sa.z * D + col]);
        const ushort4 v3 = *reinterpret_cast<const ushort4*>(&xb[(long long)sa.w * D + col]);
        const ushort4 v4 = *reinterpret_cast<const ushort4*>(&xb[(long long)sb.x * D + col]);
        const ushort4 v5 = *reinterpret_cast<const ushort4*>(&xb[(long long)sb.y * D + col]);
        const ushort4 v6 = *reinterpret_cast<const ushort4*>(&xb[(long long)sb.z * D + col]);
        const ushort4 v7 = *reinterpret_cast<const ushort4*>(&xb[(long long)sb.w * D + col]);
        BFM(m0, v0); BFM(m1, v1); BFM(m2, v2); BFM(m3, v3);
        BFM(m0, v4); BFM(m1, v5); BFM(m2, v6); BFM(m3, v7);
    }
    // ---- 4-edge chunk ----
    if (j + 4 <= end) {
        const int4 sa = *reinterpret_cast<const int4*>(&csr[j]);
        const ushort4 v0 = *reinterpret_cast<const ushort4*>(&xb[(long long)sa.x * D + col]);
        const ushort4 v1 = *reinterpret_cast<const ushort4*>(&xb[(long long)sa.y * D + col]);
        const ushort4 v2 = *reinterpret_cast<const ushort4*>(&xb[(long long)sa.z * D + col]);
        const ushort4 v3 = *reinterpret_cast<const ushort4*>(&xb[(long long)sa.w * D + col]);
        BFM(m0, v0); BFM(m1, v1); BFM(m2, v2); BFM(m3, v3);
        j += 4;
    }
    // ---- scalar tail (<=3) ----
    for (; j < end; ++j) {
        const int s = csr[j];
        const ushort4 v = *reinterpret_cast<const ushort4*>(&xb[(long long)s * D + col]);
        BFM(m0, v);
    }

    m0.x = fmaxf(fmaxf(m0.x, m1.x), fmaxf(m2.x, m3.x));
    m0.y = fmaxf(fmaxf(m0.y, m1.y), fmaxf(m2.y, m3.y));
    m0.z = fmaxf(fmaxf(m0.z, m1.z), fmaxf(m2.z, m3.z));
    m0.w = fmaxf(fmaxf(m0.w, m1.w), fmaxf(m2.w, m3.w));

    float4 c;
    if (len > 0) {
        c.x = xv.x + m0.x; c.y = xv.y + m0.y; c.z = xv.z + m0.z; c.w = xv.w + m0.w;
    } else {
        c = xv;   // empty neighborhood -> agg = 0
    }
    *reinterpret_cast<float4*>(&combined[(long long)row * D + col]) = c;
}

#undef BFM

// ---------------- persistent GEMM: out = [relu](combined @ W + b) ----------------
// WB16: also emit bf16 mirror of the output (for the next layer's gather).

template<bool RELU, bool WB16>
__global__ __launch_bounds__(256, 2) void gin_gemm_persist(
    const float* __restrict__ xc, const float* __restrict__ W,
    const float* __restrict__ b, float* __restrict__ out,
    unsigned short* __restrict__ outb)
{
    __shared__ float Wlds[D * D];        // 64 KB
    __shared__ float rowbuf[4][8][D];    // 16 KB, per-wave slice

    const int tid = threadIdx.x;

    for (int i = tid * 4; i < D * D; i += 256 * 4) {
        *reinterpret_cast<float4*>(&Wlds[i]) = *reinterpret_cast<const float4*>(&W[i]);
    }
    __syncthreads();                     // the only block-wide barrier

    const int wave = tid >> 6;
    const int lane = tid & 63;
    const int half = lane >> 5;
    const int col  = (lane & 31) * 4;
    const int r0   = half * 4;           // local row base within wave's 8 rows
    const int gw   = blockIdx.x * 4 + wave;   // global wave id

    const float4 bias = *reinterpret_cast<const float4*>(&b[col]);
    float (*rb)[D] = rowbuf[wave];

    for (int t = gw; t < N_TILES; t += GEMM_WAVES) {
        const int rbase = t * 8;

#pragma unroll
        for (int i = 0; i < 4; ++i) {
            const int idx = lane + i * 64;        // 0..255
            const int rl  = idx >> 5;
            const int c4  = (idx & 31) * 4;
            *reinterpret_cast<float4*>(&rb[rl][c4]) =
                *reinterpret_cast<const float4*>(&xc[(long long)(rbase + rl) * D + c4]);
        }

        float4 acc0 = bias, acc1 = bias, acc2 = bias, acc3 = bias;

#define GEMM_STEP(K, XA, XB, XC, XD)                                        \
    {                                                                       \
        const float4 w4 = *reinterpret_cast<const float4*>(&Wlds[(K) * D + col]); \
        acc0.x = fmaf(XA, w4.x, acc0.x); acc0.y = fmaf(XA, w4.y, acc0.y);   \
        acc0.z = fmaf(XA, w4.z, acc0.z); acc0.w = fmaf(XA, w4.w, acc0.w);   \
        acc1.x = fmaf(XB, w4.x, acc1.x); acc1.y = fmaf(XB, w4.y, acc1.y);   \
        acc1.z = fmaf(XB, w4.z, acc1.z); acc1.w = fmaf(XB, w4.w, acc1.w);   \
        acc2.x = fmaf(XC, w4.x, acc2.x); acc2.y = fmaf(XC, w4.y, acc2.y);   \
        acc2.z = fmaf(XC, w4.z, acc2.z); acc2.w = fmaf(XC, w4.w, acc2.w);   \
        acc3.x = fmaf(XD, w4.x, acc3.x); acc3.y = fmaf(XD, w4.y, acc3.y);   \
        acc3.z = fmaf(XD, w4.z, acc3.z); acc3.w = fmaf(XD, w4.w, acc3.w);   \
    }

#pragma unroll 4
        for (int kg = 0; kg < D; kg += 4) {
            const float4 xa  = *reinterpret_cast<const float4*>(&rb[r0 + 0][kg]);
            const float4 xb2 = *reinterpret_cast<const float4*>(&rb[r0 + 1][kg]);
            const float4 xc4 = *reinterpret_cast<const float4*>(&rb[r0 + 2][kg]);
            const float4 xd  = *reinterpret_cast<const float4*>(&rb[r0 + 3][kg]);
            GEMM_STEP(kg + 0, xa.x, xb2.x, xc4.x, xd.x);
            GEMM_STEP(kg + 1, xa.y, xb2.y, xc4.y, xd.y);
            GEMM_STEP(kg + 2, xa.z, xb2.z, xc4.z, xd.z);
            GEMM_STEP(kg + 3, xa.w, xb2.w, xc4.w, xd.w);
        }
#undef GEMM_STEP

        if (RELU) {
            acc0.x = fmaxf(acc0.x, 0.f); acc0.y = fmaxf(acc0.y, 0.f); acc0.z = fmaxf(acc0.z, 0.f); acc0.w = fmaxf(acc0.w, 0.f);
            acc1.x = fmaxf(acc1.x, 0.f); acc1.y = fmaxf(acc1.y, 0.f); acc1.z = fmaxf(acc1.z, 0.f); acc1.w = fmaxf(acc1.w, 0.f);
            acc2.x = fmaxf(acc2.x, 0.f); acc2.y = fmaxf(acc2.y, 0.f); acc2.z = fmaxf(acc2.z, 0.f); acc2.w = fmaxf(acc2.w, 0.f);
            acc3.x = fmaxf(acc3.x, 0.f); acc3.y = fmaxf(acc3.y, 0.f); acc3.z = fmaxf(acc3.z, 0.f); acc3.w = fmaxf(acc3.w, 0.f);
        }

        float* o = &out[(long long)(rbase + r0) * D + col];
        *reinterpret_cast<float4*>(&o[0 * D]) = acc0;
        *reinterpret_cast<float4*>(&o[1 * D]) = acc1;
        *reinterpret_cast<float4*>(&o[2 * D]) = acc2;
        *reinterpret_cast<float4*>(&o[3 * D]) = acc3;

        if (WB16) {
            unsigned short* ob = &outb[(long long)(rbase + r0) * D + col];
            ushort4 u;
            u.x = f2bf(acc0.x); u.y = f2bf(acc0.y); u.z = f2bf(acc0.z); u.w = f2bf(acc0.w);
            *reinterpret_cast<ushort4*>(&ob[0 * D]) = u;
            u.x = f2bf(acc1.x); u.y = f2bf(acc1.y); u.z = f2bf(acc1.z); u.w = f2bf(acc1.w);
            *reinterpret_cast<ushort4*>(&ob[1 * D]) = u;
            u.x = f2bf(acc2.x); u.y = f2bf(acc2.y); u.z = f2bf(acc2.z); u.w = f2bf(acc2.w);
            *reinterpret_cast<ushort4*>(&ob[2 * D]) = u;
            u.x = f2bf(acc3.x); u.y = f2bf(acc3.y); u.z = f2bf(acc3.z); u.w = f2bf(acc3.w);
            *reinterpret_cast<ushort4*>(&ob[3 * D]) = u;
        }
    }
}

// ---------------- launch ----------------

extern "C" void kernel_launch(void* const* d_in, const int* in_sizes, int n_in,
                              void* d_out, int out_size, void* d_ws, size_t ws_size,
                              hipStream_t stream) {
    const float* h   = (const float*)d_in[0];
    const int*   src = (const int*)d_in[1];
    const int*   dst = (const int*)d_in[2];
    const float* W1  = (const float*)d_in[3];
    const float* b1  = (const float*)d_in[4];
    const float* W2  = (const float*)d_in[5];
    const float* b2  = (const float*)d_in[6];
    float* out = (float*)d_out;

    // workspace layout (16B aligned chunks)
    int* cnt         = (int*)d_ws;                            // [100352]
    int* bucketBase  = cnt + 100352;                          // [512 reserved; 8 used]
    int* csr         = bucketBase + 512;                      // [N * PAD] = 25.6 MB
    unsigned* bstore = (unsigned*)(csr + (size_t)N_NODES * PAD); // [8 * 262144] = 8 MB
    float* combined  = (float*)(bstore + (size_t)NB * BUCKET_CAP); // [N*D] = 51.2 MB
    float* x1        = combined + (size_t)N_NODES * D;             // [N*D] = 51.2 MB
    unsigned short* xb  = (unsigned short*)(x1 + (size_t)N_NODES * D); // [N*D] bf16 = 25.6 MB
    unsigned short* x1b = xb + (size_t)N_NODES * D;                    // [N*D] bf16 = 25.6 MB

    // ---- CSR build + h->bf16 mirror ----
    hipMemsetAsync(bucketBase, 0, NB * sizeof(int), stream);
    bucket_edges<<<P1_BLOCKS, 256, 0, stream>>>(src, dst, bucketBase, bstore,
                                                h, (uint4*)xb);
    scatter_filter<<<NB * SC_CHUNKS, 1024, 0, stream>>>(bstore, bucketBase, cnt, csr);

    // ---- layer 1 (bf16 gather; fp32 self + GEMM; emits x1 + x1b) ----
    agg_combine_kernel<<<NB * AGG_CHUNKS, 256, 0, stream>>>(h, xb, cnt, csr, combined);
    gin_gemm_persist<true, true><<<GEMM_BLOCKS, 256, 0, stream>>>(combined, W1, b1, x1, x1b);

    // ---- layer 2 ----
    agg_combine_kernel<<<NB * AGG_CHUNKS, 256, 0, stream>>>(x1, x1b, cnt, csr, combined);
    gin_gemm_persist<false, false><<<GEMM_BLOCKS, 256, 0, stream>>>(combined, W2, b2, out, nullptr);
}